// Round 12
// baseline (99.964 us; speedup 1.0000x reference)
//
#include <hip/hip_runtime.h>
#include <hip/hip_bf16.h>

typedef __attribute__((ext_vector_type(8))) short bf16x8;
typedef __attribute__((ext_vector_type(4))) short bf16x4;
typedef __attribute__((ext_vector_type(4))) float f32x4;

#if defined(__has_builtin)
#if __has_builtin(__builtin_amdgcn_exp2f)
#define EXP2F(x) __builtin_amdgcn_exp2f(x)
#else
#define EXP2F(x) exp2f(x)
#endif
#else
#define EXP2F(x) exp2f(x)
#endif

#define S_LEN 2048
#define NH 32
#define HD 32
#define DMODEL 1024
#define NB 2

// pack two fp32 -> two bf16 (RNE) in one instruction
static __device__ __forceinline__ unsigned int cvt_pk_bf16(float lo, float hi) {
    unsigned int r;
    asm("v_cvt_pk_bf16_f32 %0, %1, %2" : "=v"(r) : "v"(lo), "v"(hi));
    return r;
}

// ---------------------------------------------------------------------------
// Kernel 1: MFMA QKV projection (R11-verified)
// ---------------------------------------------------------------------------
__global__ __launch_bounds__(256) void qkv_mfma(
    const float* __restrict__ x,
    const float* __restrict__ wq, const float* __restrict__ bq,
    const float* __restrict__ wk, const float* __restrict__ bk,
    const float* __restrict__ wv, const float* __restrict__ bv,
    __hip_bfloat16* __restrict__ qws,
    __hip_bfloat16* __restrict__ kws,
    __hip_bfloat16* __restrict__ vtws)
{
    const int tid = threadIdx.x;
    const int w  = tid >> 6;
    const int ln = tid & 63;
    const int lg = ln >> 4, lm = ln & 15;

    const int bi = blockIdx.x;          // 0..1023
    const int tb = bi >> 2;             // token-16 block 0..255
    const int hq = bi & 3;              // head quarter
    const int t0 = tb * 16;             // flat token base (b*S + s)
    const int b  = t0 >> 11;
    const int s0 = t0 & 2047;

    const float SC = 0.1767766953f * 1.44269504089f;

    // --- loop-invariant W fragments ---
    bf16x8 wqB[2], wkB[2], wvA[2];
    f32x4 bqC[2], bkC[2], bvC[2];
#pragma unroll
    for (int et = 0; et < 2; ++et) {
        const int e = et * 16 + lm;
        union { unsigned int u4[4]; bf16x8 v; } tq, tk, tv;
#pragma unroll
        for (int jj = 0; jj < 4; ++jj) {
            int k0 = lg * 8 + jj * 2;
            tq.u4[jj] = cvt_pk_bf16(wq[k0 * 32 + e] * SC, wq[(k0 + 1) * 32 + e] * SC);
            tk.u4[jj] = cvt_pk_bf16(wk[k0 * 32 + e],      wk[(k0 + 1) * 32 + e]);
            tv.u4[jj] = cvt_pk_bf16(wv[k0 * 32 + e],      wv[(k0 + 1) * 32 + e]);
        }
        wqB[et] = tq.v; wkB[et] = tk.v; wvA[et] = tv.v;

        float bqe = bq[e] * SC;
        float bke = bk[e];
        bqC[et] = (f32x4){bqe, bqe, bqe, bqe};
        bkC[et] = (f32x4){bke, bke, bke, bke};
#pragma unroll
        for (int r = 0; r < 4; ++r)
            bvC[et][r] = bv[et * 16 + lg * 4 + r];
    }

#pragma unroll
    for (int u = 0; u < 2; ++u) {
        const int h = hq * 8 + w * 2 + u;

        // x fragment: x[token t0+lm][h*32 + lg*8 + 0..7] (fp32 -> bf16)
        const float* xp = x + (size_t)(t0 + lm) * DMODEL + h * 32 + lg * 8;
        float4 xlo = *reinterpret_cast<const float4*>(xp);
        float4 xhi = *reinterpret_cast<const float4*>(xp + 4);
        union { unsigned int u4[4]; bf16x8 v; } xa;
        xa.u4[0] = cvt_pk_bf16(xlo.x, xlo.y);
        xa.u4[1] = cvt_pk_bf16(xlo.z, xlo.w);
        xa.u4[2] = cvt_pk_bf16(xhi.x, xhi.y);
        xa.u4[3] = cvt_pk_bf16(xhi.z, xhi.w);

        const int bh = b * NH + h;
        __hip_bfloat16* qrow = qws + ((size_t)bh * S_LEN + s0) * HD;
        __hip_bfloat16* krow = kws + ((size_t)bh * S_LEN + s0) * HD;
        __hip_bfloat16* vrow = vtws + (size_t)bh * HD * S_LEN + s0;

#pragma unroll
        for (int et = 0; et < 2; ++et) {
            f32x4 qd = __builtin_amdgcn_mfma_f32_16x16x32_bf16(xa.v, wqB[et], bqC[et], 0, 0, 0);
            f32x4 kd = __builtin_amdgcn_mfma_f32_16x16x32_bf16(xa.v, wkB[et], bkC[et], 0, 0, 0);
            f32x4 vd = __builtin_amdgcn_mfma_f32_16x16x32_bf16(wvA[et], xa.v, bvC[et], 0, 0, 0);
#pragma unroll
            for (int r = 0; r < 4; ++r) {
                int srow = 4 * lg + r;          // token offset within the 16
                qrow[(size_t)srow * HD + et * 16 + lm] = __float2bfloat16(qd[r]);
                krow[(size_t)srow * HD + et * 16 + lm] = __float2bfloat16(kd[r]);
                vrow[(size_t)(et * 16 + 4 * lg + r) * S_LEN + lm] = __float2bfloat16(vd[r]);
            }
        }
    }
}

// ---------------------------------------------------------------------------
// Kernel 2: wo [K][N] fp32 -> wot [N][K] bf16 (unchanged, verified)
// ---------------------------------------------------------------------------
__global__ __launch_bounds__(256) void wo_transpose(
    const float* __restrict__ wo, __hip_bfloat16* __restrict__ wot)
{
    __shared__ float t[64][65];
    const int bx = blockIdx.x;
    const int by = blockIdx.y;
    const int tid = threadIdx.x;
    const int col = tid & 63, row4 = tid >> 6;
#pragma unroll
    for (int i = 0; i < 16; ++i) {
        int r = i * 4 + row4;
        t[r][col] = wo[(size_t)(bx * 64 + r) * DMODEL + by * 64 + col];
    }
    __syncthreads();
#pragma unroll
    for (int i = 0; i < 16; ++i) {
        int r = i * 4 + row4;
        wot[(size_t)(by * 64 + r) * DMODEL + bx * 64 + col] =
            __float2bfloat16(t[col][r]);
    }
}

// ---------------------------------------------------------------------------
// Kernel 3: flash attention — R11 structure with DOUBLE-BUFFERED K/V tile.
// Per iteration: compute buf[cur] -> write next tile to buf[cur^1] ->
// issue loads for kt+2 -> ONE barrier. Compute never waits on staging;
// loads stay in flight across a full compute phase. All fragment math,
// softmax, P strip, and epilogue byte-identical to the R8/R11 passing code.
// ---------------------------------------------------------------------------
__global__ __launch_bounds__(256) void attn_kernel(
    const __hip_bfloat16* __restrict__ qws,
    const __hip_bfloat16* __restrict__ kws,
    const __hip_bfloat16* __restrict__ vtws,
    __hip_bfloat16* __restrict__ cws)
{
    const int tid = threadIdx.x;
    const int w  = tid >> 6;
    const int ln = tid & 63;
    const int lg = ln >> 4;   // 16-lane group 0..3
    const int lm = ln & 15;

    // XCD-aware decode (R5-verified): heads 8x..8x+7 pinned to XCD x
    const int bi  = blockIdx.x;
    const int xcd = bi & 7;
    const int idx = bi >> 3;                   // 0..255
    const int qt  = idx & 31;
    const int bh  = (xcd << 3) | (idx >> 5);   // b*32+h
    const int b   = bh >> 5;
    const int h   = bh & 31;

    const __hip_bfloat16* qp = qws + (size_t)bh * S_LEN * HD;
    const char* kpb = (const char*)(kws  + (size_t)bh * S_LEN * HD);
    const char* vpb = (const char*)(vtws + (size_t)bh * HD * S_LEN);

    const int qr0 = qt * 64 + w * 16;

    // Q as B-fragment: col = q = lm, k = d = lg*8+j
    bf16x8 qb = *reinterpret_cast<const bf16x8*>(qp + (size_t)(qr0 + lm) * HD + lg * 8);

    // LDS: double-buffered {K tile 4KB linear | V tile 4KB slot-swizzled}
    __shared__ __align__(16) char kv[2][8192];
    __shared__ __align__(16) __hip_bfloat16 plds_all[4][16][72];
    __hip_bfloat16 (*plds)[72] = plds_all[w];

    f32x4 l4 = {0.f, 0.f, 0.f, 0.f};
    f32x4 o0 = {0.f, 0.f, 0.f, 0.f};   // O^T[d=4lg+r][q=lm]
    f32x4 o1 = {0.f, 0.f, 0.f, 0.f};   // O^T[16+4lg+r][q=lm]
    const f32x4 zoff = {-8.f, -8.f, -8.f, -8.f};

    // staging addresses: thread tid owns 16B slot tid of each tile
    const int vrow  = tid >> 3;                       // V^T row (d), 0..31
    const int vslot = tid & 7;                        // 16B slot within row
    const size_t vsrc = (size_t)vrow * (S_LEN * 2) +
                        (size_t)(vslot ^ (vrow & 7)) * 16;   // swizzled source

    const int NT = S_LEN / 64;

    // prologue: stage tile 0 into buf0, issue loads for tile 1
    uint4 kreg = *reinterpret_cast<const uint4*>(kpb + tid * 16);
    uint4 vreg = *reinterpret_cast<const uint4*>(vpb + vsrc);
    *reinterpret_cast<uint4*>(&kv[0][tid * 16])        = kreg;
    *reinterpret_cast<uint4*>(&kv[0][4096 + tid * 16]) = vreg;
    kreg = *reinterpret_cast<const uint4*>(kpb + 4096 + tid * 16);
    vreg = *reinterpret_cast<const uint4*>(vpb + vsrc + 128);
    __syncthreads();

    for (int kt = 0; kt < NT; ++kt) {
        const int cur = kt & 1;
        const char* Kl = kv[cur];
        const char* Vl = kv[cur] + 4096;

        // S^T chunks: s[c][r] = score(q=lm, k=16c+4lg+r) - 8
        f32x4 s[4];
#pragma unroll
        for (int c = 0; c < 4; ++c) {
            bf16x8 kf = *reinterpret_cast<const bf16x8*>(
                Kl + c * 1024 + lm * 64 + lg * 16);
            s[c] = __builtin_amdgcn_mfma_f32_16x16x32_bf16(kf, qb, zoff, 0, 0, 0);
        }

        // p = exp2(s-8); accumulate denominator; pack into P[q][k] LDS strip
#pragma unroll
        for (int c = 0; c < 4; ++c) {
            float p0 = EXP2F(s[c][0]);
            float p1 = EXP2F(s[c][1]);
            float p2 = EXP2F(s[c][2]);
            float p3 = EXP2F(s[c][3]);
            l4[0] += p0; l4[1] += p1; l4[2] += p2; l4[3] += p3;
            *reinterpret_cast<uint2*>(&plds[lm][c * 16 + lg * 4]) =
                make_uint2(cvt_pk_bf16(p0, p1), cvt_pk_bf16(p2, p3));
        }

        // PV: O^T += V^T * P^T; A = V^T rows from swizzled LDS (16B reads)
#pragma unroll
        for (int ks = 0; ks < 2; ++ks) {
            bf16x8 pa = *reinterpret_cast<const bf16x8*>(
                &plds[lm][ks * 32 + lg * 8]);
            int j = (ks * 4 + lg) ^ (lm & 7);
            bf16x8 va = *reinterpret_cast<const bf16x8*>(
                Vl + lm * 128 + j * 16);
            o0 = __builtin_amdgcn_mfma_f32_16x16x32_bf16(va, pa, o0, 0, 0, 0);
            bf16x8 vb = *reinterpret_cast<const bf16x8*>(
                Vl + (lm + 16) * 128 + j * 16);
            o1 = __builtin_amdgcn_mfma_f32_16x16x32_bf16(vb, pa, o1, 0, 0, 0);
        }

        // stage next tile into the other buffer, then prefetch tile kt+2
        if (kt + 1 < NT) {
            char* Kn = kv[cur ^ 1];
            *reinterpret_cast<uint4*>(&Kn[tid * 16])        = kreg;
            *reinterpret_cast<uint4*>(&Kn[4096 + tid * 16]) = vreg;
            if (kt + 2 < NT) {
                kreg = *reinterpret_cast<const uint4*>(
                    kpb + (size_t)(kt + 2) * 4096 + tid * 16);
                vreg = *reinterpret_cast<const uint4*>(
                    vpb + vsrc + (size_t)(kt + 2) * 128);
            }
        }
        __syncthreads();
    }

    // final denominator: reduce partial l across the 4 lg groups of column lm
    float l = (l4[0] + l4[1]) + (l4[2] + l4[3]);
    l += __shfl_xor(l, 16);
    l += __shfl_xor(l, 32);
    float inv = 1.0f / l;

    __hip_bfloat16* cb = cws + ((size_t)b * S_LEN + qr0 + lm) * DMODEL + h * HD;
    union { unsigned int u[2]; bf16x4 v; } w0, w1;
    w0.u[0] = cvt_pk_bf16(o0[0] * inv, o0[1] * inv);
    w0.u[1] = cvt_pk_bf16(o0[2] * inv, o0[3] * inv);
    w1.u[0] = cvt_pk_bf16(o1[0] * inv, o1[1] * inv);
    w1.u[1] = cvt_pk_bf16(o1[2] * inv, o1[3] * inv);
    *reinterpret_cast<bf16x4*>(cb + lg * 4)      = w0.v;
    *reinterpret_cast<bf16x4*>(cb + 16 + lg * 4) = w1.v;
}

// ---------------------------------------------------------------------------
// Kernel 4: out = concat @ wo + bo — LDS-tiled (unchanged from R8, verified)
// ---------------------------------------------------------------------------
__global__ __launch_bounds__(256) void out_gemm(
    const __hip_bfloat16* __restrict__ A,
    const __hip_bfloat16* __restrict__ Bt,
    const float* __restrict__ bo,
    float* __restrict__ out)
{
    const int tid = threadIdx.x;
    const int ln = tid & 63;
    const int w  = tid >> 6;
    const int lg = ln >> 4, lm = ln & 15;
    const int wr = w >> 1, wc = w & 1;
    const int bi = blockIdx.x;
    const int bn = bi & 7;
    const int bm = bi >> 3;
    const int r0 = bm * 64;
    const int n0 = bn * 128;

    __shared__ __align__(16) char lds[24576];

    f32x4 acc[2][4];
#pragma unroll
    for (int m = 0; m < 2; ++m)
#pragma unroll
        for (int n = 0; n < 4; ++n)
            acc[m][n] = {0.f, 0.f, 0.f, 0.f};

    const int srow = tid >> 3;
    const int sj   = tid & 7;
    const int swo  = srow * 128 + ((sj ^ (srow & 7)) << 4);

    const __hip_bfloat16* Ab = A  + (size_t)r0 * DMODEL;
    const __hip_bfloat16* Bb = Bt + (size_t)n0 * DMODEL;

    uint4 ar0 = *reinterpret_cast<const uint4*>(Ab + (size_t)srow        * DMODEL + sj * 8);
    uint4 ar1 = *reinterpret_cast<const uint4*>(Ab + (size_t)(srow + 32) * DMODEL + sj * 8);
    uint4 br0 = *reinterpret_cast<const uint4*>(Bb + (size_t)srow        * DMODEL + sj * 8);
    uint4 br1 = *reinterpret_cast<const uint4*>(Bb + (size_t)(srow + 32) * DMODEL + sj * 8);
    uint4 br2 = *reinterpret_cast<const uint4*>(Bb + (size_t)(srow + 64) * DMODEL + sj * 8);
    uint4 br3 = *reinterpret_cast<const uint4*>(Bb + (size_t)(srow + 96) * DMODEL + sj * 8);

    for (int k0 = 0; k0 < DMODEL; k0 += 64) {
        if (k0) __syncthreads();
        *reinterpret_cast<uint4*>(&lds[swo])          = ar0;
        *reinterpret_cast<uint4*>(&lds[swo + 4096])   = ar1;
        *reinterpret_cast<uint4*>(&lds[8192 + swo])           = br0;
        *reinterpret_cast<uint4*>(&lds[8192 + swo + 4096])    = br1;
        *reinterpret_cast<uint4*>(&lds[8192 + swo + 8192])    = br2;
        *reinterpret_cast<uint4*>(&lds[8192 + swo + 12288])   = br3;
        __syncthreads();
        if (k0 + 64 < DMODEL) {
            const __hip_bfloat16* An = Ab + k0 + 64;
            const __hip_bfloat16* Bn = Bb + k0 + 64;
            ar0 = *reinterpret_cast<const uint4*>(An + (size_t)srow        * DMODEL + sj * 8);
            ar1 = *reinterpret_cast<const uint4*>(An + (size_t)(srow + 32) * DMODEL + sj * 8);
            br0 = *reinterpret_cast<const uint4*>(Bn + (size_t)srow        * DMODEL + sj * 8);
            br1 = *reinterpret_cast<const uint4*>(Bn + (size_t)(srow + 32) * DMODEL + sj * 8);
            br2 = *reinterpret_cast<const uint4*>(Bn + (size_t)(srow + 64) * DMODEL + sj * 8);
            br3 = *reinterpret_cast<const uint4*>(Bn + (size_t)(srow + 96) * DMODEL + sj * 8);
        }

#pragma unroll
        for (int kh = 0; kh < 2; ++kh) {
            bf16x8 af[2], bf[4];
#pragma unroll
            for (int m = 0; m < 2; ++m) {
                int row = wr * 32 + m * 16 + lm;
                af[m] = *reinterpret_cast<const bf16x8*>(
                    &lds[row * 128 + (((kh * 4 + lg) ^ (row & 7)) << 4)]);
            }
#pragma unroll
            for (int n = 0; n < 4; ++n) {
                int row = wc * 64 + n * 16 + lm;
                bf[n] = *reinterpret_cast<const bf16x8*>(
                    &lds[8192 + row * 128 + (((kh * 4 + lg) ^ (row & 7)) << 4)]);
            }
#pragma unroll
            for (int m = 0; m < 2; ++m)
#pragma unroll
                for (int n = 0; n < 4; ++n)
                    acc[m][n] = __builtin_amdgcn_mfma_f32_16x16x32_bf16(
                        af[m], bf[n], acc[m][n], 0, 0, 0);
        }
    }

#pragma unroll
    for (int n = 0; n < 4; ++n) {
        int col = n0 + wc * 64 + n * 16 + lm;
        float bv = bo[col];
#pragma unroll
        for (int m = 0; m < 2; ++m) {
#pragma unroll
            for (int r = 0; r < 4; ++r) {
                int row = r0 + wr * 32 + m * 16 + lg * 4 + r;
                out[(size_t)row * DMODEL + col] = acc[m][n][r] + bv;
            }
        }
    }
}

// ---------------------------------------------------------------------------
extern "C" void kernel_launch(void* const* d_in, const int* in_sizes, int n_in,
                              void* d_out, int out_size, void* d_ws, size_t ws_size,
                              hipStream_t stream)
{
    const float* x  = (const float*)d_in[0];
    const float* wq = (const float*)d_in[1];
    const float* bq = (const float*)d_in[2];
    const float* wk = (const float*)d_in[3];
    const float* bk = (const float*)d_in[4];
    const float* wv = (const float*)d_in[5];
    const float* bv = (const float*)d_in[6];
    const float* wo = (const float*)d_in[7];
    const float* bo = (const float*)d_in[8];
    float* out = (float*)d_out;

    char* ws = (char*)d_ws;
    __hip_bfloat16* qws  = (__hip_bfloat16*)(ws);                        // 8 MB
    __hip_bfloat16* kws  = (__hip_bfloat16*)(ws + ((size_t)8  << 20));   // 8 MB
    __hip_bfloat16* vtws = (__hip_bfloat16*)(ws + ((size_t)16 << 20));   // 8 MB
    __hip_bfloat16* cws  = (__hip_bfloat16*)(ws + ((size_t)24 << 20));   // 8 MB
    __hip_bfloat16* wot  = (__hip_bfloat16*)(ws + ((size_t)32 << 20));   // 2 MB

    qkv_mfma<<<1024, 256, 0, stream>>>(
        x, wq, bq, wk, bk, wv, bv, qws, kws, vtws);
    wo_transpose<<<dim3(16, 16), 256, 0, stream>>>(wo, wot);
    attn_kernel<<<NB * NH * (S_LEN / 64), 256, 0, stream>>>(qws, kws, vtws, cws);
    out_gemm<<<(NB * S_LEN / 64) * (DMODEL / 128), 256, 0, stream>>>(
        cws, wot, bo, out);
}

// Round 13
// 98.376 us; speedup vs baseline: 1.0161x; 1.0161x over previous
//
#include <hip/hip_runtime.h>
#include <hip/hip_bf16.h>

typedef __attribute__((ext_vector_type(8))) short bf16x8;
typedef __attribute__((ext_vector_type(4))) short bf16x4;
typedef __attribute__((ext_vector_type(4))) float f32x4;

#if defined(__has_builtin)
#if __has_builtin(__builtin_amdgcn_exp2f)
#define EXP2F(x) __builtin_amdgcn_exp2f(x)
#else
#define EXP2F(x) exp2f(x)
#endif
#else
#define EXP2F(x) exp2f(x)
#endif

#define S_LEN 2048
#define NH 32
#define HD 32
#define DMODEL 1024
#define NB 2

// pack two fp32 -> two bf16 (RNE) in one instruction
static __device__ __forceinline__ unsigned int cvt_pk_bf16(float lo, float hi) {
    unsigned int r;
    asm("v_cvt_pk_bf16_f32 %0, %1, %2" : "=v"(r) : "v"(lo), "v"(hi));
    return r;
}

// K=16 bf16 MFMA, accumulate-only use (D read once, in the epilogue).
// Non-volatile: pure dataflow, "+v" ties C/D. Leading s_nop 2 covers the
// VALU-write -> MFMA-read src hazard. R2 proved instruction+layout correct;
// R2/R5's cost was volatile + per-MFMA trailing s_nop7 pairs (removed here).
static __device__ __forceinline__ void mfma16_acc(f32x4& d, bf16x4 a, bf16x4 b) {
    asm("s_nop 2\n\tv_mfma_f32_16x16x16_bf16 %0, %1, %2, %0"
        : "+v"(d) : "v"(a), "v"(b));
}

// ---------------------------------------------------------------------------
// Kernel 1: MFMA QKV projection (R11-verified)
// ---------------------------------------------------------------------------
__global__ __launch_bounds__(256) void qkv_mfma(
    const float* __restrict__ x,
    const float* __restrict__ wq, const float* __restrict__ bq,
    const float* __restrict__ wk, const float* __restrict__ bk,
    const float* __restrict__ wv, const float* __restrict__ bv,
    __hip_bfloat16* __restrict__ qws,
    __hip_bfloat16* __restrict__ kws,
    __hip_bfloat16* __restrict__ vtws)
{
    const int tid = threadIdx.x;
    const int w  = tid >> 6;
    const int ln = tid & 63;
    const int lg = ln >> 4, lm = ln & 15;

    const int bi = blockIdx.x;          // 0..1023
    const int tb = bi >> 2;             // token-16 block 0..255
    const int hq = bi & 3;              // head quarter
    const int t0 = tb * 16;             // flat token base (b*S + s)
    const int b  = t0 >> 11;
    const int s0 = t0 & 2047;

    const float SC = 0.1767766953f * 1.44269504089f;

    // --- loop-invariant W fragments ---
    bf16x8 wqB[2], wkB[2], wvA[2];
    f32x4 bqC[2], bkC[2], bvC[2];
#pragma unroll
    for (int et = 0; et < 2; ++et) {
        const int e = et * 16 + lm;
        union { unsigned int u4[4]; bf16x8 v; } tq, tk, tv;
#pragma unroll
        for (int jj = 0; jj < 4; ++jj) {
            int k0 = lg * 8 + jj * 2;
            tq.u4[jj] = cvt_pk_bf16(wq[k0 * 32 + e] * SC, wq[(k0 + 1) * 32 + e] * SC);
            tk.u4[jj] = cvt_pk_bf16(wk[k0 * 32 + e],      wk[(k0 + 1) * 32 + e]);
            tv.u4[jj] = cvt_pk_bf16(wv[k0 * 32 + e],      wv[(k0 + 1) * 32 + e]);
        }
        wqB[et] = tq.v; wkB[et] = tk.v; wvA[et] = tv.v;

        float bqe = bq[e] * SC;
        float bke = bk[e];
        bqC[et] = (f32x4){bqe, bqe, bqe, bqe};
        bkC[et] = (f32x4){bke, bke, bke, bke};
#pragma unroll
        for (int r = 0; r < 4; ++r)
            bvC[et][r] = bv[et * 16 + lg * 4 + r];
    }

#pragma unroll
    for (int u = 0; u < 2; ++u) {
        const int h = hq * 8 + w * 2 + u;

        const float* xp = x + (size_t)(t0 + lm) * DMODEL + h * 32 + lg * 8;
        float4 xlo = *reinterpret_cast<const float4*>(xp);
        float4 xhi = *reinterpret_cast<const float4*>(xp + 4);
        union { unsigned int u4[4]; bf16x8 v; } xa;
        xa.u4[0] = cvt_pk_bf16(xlo.x, xlo.y);
        xa.u4[1] = cvt_pk_bf16(xlo.z, xlo.w);
        xa.u4[2] = cvt_pk_bf16(xhi.x, xhi.y);
        xa.u4[3] = cvt_pk_bf16(xhi.z, xhi.w);

        const int bh = b * NH + h;
        __hip_bfloat16* qrow = qws + ((size_t)bh * S_LEN + s0) * HD;
        __hip_bfloat16* krow = kws + ((size_t)bh * S_LEN + s0) * HD;
        __hip_bfloat16* vrow = vtws + (size_t)bh * HD * S_LEN + s0;

#pragma unroll
        for (int et = 0; et < 2; ++et) {
            f32x4 qd = __builtin_amdgcn_mfma_f32_16x16x32_bf16(xa.v, wqB[et], bqC[et], 0, 0, 0);
            f32x4 kd = __builtin_amdgcn_mfma_f32_16x16x32_bf16(xa.v, wkB[et], bkC[et], 0, 0, 0);
            f32x4 vd = __builtin_amdgcn_mfma_f32_16x16x32_bf16(wvA[et], xa.v, bvC[et], 0, 0, 0);
#pragma unroll
            for (int r = 0; r < 4; ++r) {
                int srow = 4 * lg + r;
                qrow[(size_t)srow * HD + et * 16 + lm] = __float2bfloat16(qd[r]);
                krow[(size_t)srow * HD + et * 16 + lm] = __float2bfloat16(kd[r]);
                vrow[(size_t)(et * 16 + 4 * lg + r) * S_LEN + lm] = __float2bfloat16(vd[r]);
            }
        }
    }
}

// ---------------------------------------------------------------------------
// Kernel 2: wo [K][N] fp32 -> wot [N][K] bf16 (unchanged, verified)
// ---------------------------------------------------------------------------
__global__ __launch_bounds__(256) void wo_transpose(
    const float* __restrict__ wo, __hip_bfloat16* __restrict__ wot)
{
    __shared__ float t[64][65];
    const int bx = blockIdx.x;
    const int by = blockIdx.y;
    const int tid = threadIdx.x;
    const int col = tid & 63, row4 = tid >> 6;
#pragma unroll
    for (int i = 0; i < 16; ++i) {
        int r = i * 4 + row4;
        t[r][col] = wo[(size_t)(bx * 64 + r) * DMODEL + by * 64 + col];
    }
    __syncthreads();
#pragma unroll
    for (int i = 0; i < 16; ++i) {
        int r = i * 4 + row4;
        wot[(size_t)(by * 64 + r) * DMODEL + bx * 64 + col] =
            __float2bfloat16(t[col][r]);
    }
}

// ---------------------------------------------------------------------------
// Kernel 3: flash attention — R11 loop structure (single K/V buffer, proven
// 75us) with the P LDS round-trip DELETED: PV runs as 8x K=16 asm MFMA with
// P straight from registers (S^T C-layout == K=16 B-fragment, R2-proven).
// V fragments: 8B reads from the swizzled LDS V-tile,
//   slot' = (2c + (lg>>1)) ^ (lm&7), byte = lm*128 + slot'*16 + (lg&1)*8.
// LDS: 8192 B (K tile + V tile only). Per-wave-iter LDS phases 112 -> 80.
// ---------------------------------------------------------------------------
__global__ __launch_bounds__(256) void attn_kernel(
    const __hip_bfloat16* __restrict__ qws,
    const __hip_bfloat16* __restrict__ kws,
    const __hip_bfloat16* __restrict__ vtws,
    __hip_bfloat16* __restrict__ cws)
{
    const int tid = threadIdx.x;
    const int w  = tid >> 6;
    const int ln = tid & 63;
    const int lg = ln >> 4;   // 16-lane group 0..3
    const int lm = ln & 15;

    // XCD-aware decode (R5-verified): heads 8x..8x+7 pinned to XCD x
    const int bi  = blockIdx.x;
    const int xcd = bi & 7;
    const int idx = bi >> 3;                   // 0..255
    const int qt  = idx & 31;
    const int bh  = (xcd << 3) | (idx >> 5);   // b*32+h
    const int b   = bh >> 5;
    const int h   = bh & 31;

    const __hip_bfloat16* qp = qws + (size_t)bh * S_LEN * HD;
    const char* kpb = (const char*)(kws  + (size_t)bh * S_LEN * HD);
    const char* vpb = (const char*)(vtws + (size_t)bh * HD * S_LEN);

    const int qr0 = qt * 64 + w * 16;

    // Q as B-fragment: col = q = lm, k = d = lg*8+j
    bf16x8 qb = *reinterpret_cast<const bf16x8*>(qp + (size_t)(qr0 + lm) * HD + lg * 8);

    // LDS: K tile [0,4096) linear; V tile [4096,8192) 16B-slot swizzled
    __shared__ __align__(16) char kv[8192];

    f32x4 l4 = {0.f, 0.f, 0.f, 0.f};
    f32x4 o0 = {0.f, 0.f, 0.f, 0.f};   // O^T[d=4lg+r][q=lm]
    f32x4 o1 = {0.f, 0.f, 0.f, 0.f};   // O^T[16+4lg+r][q=lm]
    const f32x4 zoff = {-8.f, -8.f, -8.f, -8.f};

    // staging addresses: thread tid owns 16B slot tid of each tile
    const int vrow  = tid >> 3;                       // V^T row (d), 0..31
    const int vslot = tid & 7;                        // 16B slot within row
    const size_t vsrc = (size_t)vrow * (S_LEN * 2) +
                        (size_t)(vslot ^ (vrow & 7)) * 16;   // swizzled source

    // V-read LDS byte offsets (loop-invariant): per c, slot'=(2c+(lg>>1))^(lm&7)
    int voff[4];
#pragma unroll
    for (int c = 0; c < 4; ++c)
        voff[c] = 4096 + lm * 128 + (((2 * c + (lg >> 1)) ^ (lm & 7)) << 4) + (lg & 1) * 8;

    // prologue: load tile 0 into registers
    uint4 kreg = *reinterpret_cast<const uint4*>(kpb + tid * 16);
    uint4 vreg = *reinterpret_cast<const uint4*>(vpb + vsrc);

    for (int kt = 0; kt < S_LEN / 64; ++kt) {
        if (kt) __syncthreads();                      // readers done with buffer
        *reinterpret_cast<uint4*>(&kv[tid * 16])        = kreg;
        *reinterpret_cast<uint4*>(&kv[4096 + tid * 16]) = vreg;
        __syncthreads();                              // staged data visible
        if (kt + 1 < S_LEN / 64) {                    // issue next-tile loads now
            kreg = *reinterpret_cast<const uint4*>(
                kpb + (size_t)(kt + 1) * 4096 + tid * 16);
            vreg = *reinterpret_cast<const uint4*>(
                vpb + vsrc + (size_t)(kt + 1) * 128);
        }

        // S^T chunks: s[c][r] = score(q=lm, k=16c+4lg+r) - 8
        f32x4 s[4];
#pragma unroll
        for (int c = 0; c < 4; ++c) {
            bf16x8 kf = *reinterpret_cast<const bf16x8*>(
                &kv[c * 1024 + lm * 64 + lg * 16]);
            s[c] = __builtin_amdgcn_mfma_f32_16x16x32_bf16(kf, qb, zoff, 0, 0, 0);
        }

        // p = exp2(s-8); accumulate denominator; pack into K=16 B-fragments
        bf16x4 pb[4];
#pragma unroll
        for (int c = 0; c < 4; ++c) {
            float p0 = EXP2F(s[c][0]);
            float p1 = EXP2F(s[c][1]);
            float p2 = EXP2F(s[c][2]);
            float p3 = EXP2F(s[c][3]);
            l4[0] += p0; l4[1] += p1; l4[2] += p2; l4[3] += p3;
            union { unsigned int u[2]; bf16x4 v; } pk_;
            pk_.u[0] = cvt_pk_bf16(p0, p1);
            pk_.u[1] = cvt_pk_bf16(p2, p3);
            pb[c] = pk_.v;
        }

        // PV: O^T += V^T * P^T, K=16 per kv-chunk, P from registers
#pragma unroll
        for (int c = 0; c < 4; ++c) {
            bf16x4 va = *reinterpret_cast<const bf16x4*>(&kv[voff[c]]);
            bf16x4 vb = *reinterpret_cast<const bf16x4*>(&kv[voff[c] + 2048]); // row lm+16
            mfma16_acc(o0, va, pb[c]);
            mfma16_acc(o1, vb, pb[c]);
        }
    }

    // MFMA->VALU read-of-D hazard guard (one-time), then epilogue
    asm volatile("s_nop 7\n\ts_nop 7");

    float l = (l4[0] + l4[1]) + (l4[2] + l4[3]);
    l += __shfl_xor(l, 16);
    l += __shfl_xor(l, 32);
    float inv = 1.0f / l;

    __hip_bfloat16* cb = cws + ((size_t)b * S_LEN + qr0 + lm) * DMODEL + h * HD;
    union { unsigned int u[2]; bf16x4 v; } w0, w1;
    w0.u[0] = cvt_pk_bf16(o0[0] * inv, o0[1] * inv);
    w0.u[1] = cvt_pk_bf16(o0[2] * inv, o0[3] * inv);
    w1.u[0] = cvt_pk_bf16(o1[0] * inv, o1[1] * inv);
    w1.u[1] = cvt_pk_bf16(o1[2] * inv, o1[3] * inv);
    *reinterpret_cast<bf16x4*>(cb + lg * 4)      = w0.v;
    *reinterpret_cast<bf16x4*>(cb + 16 + lg * 4) = w1.v;
}

// ---------------------------------------------------------------------------
// Kernel 4: out = concat @ wo + bo — LDS-tiled (unchanged from R8, verified)
// ---------------------------------------------------------------------------
__global__ __launch_bounds__(256) void out_gemm(
    const __hip_bfloat16* __restrict__ A,
    const __hip_bfloat16* __restrict__ Bt,
    const float* __restrict__ bo,
    float* __restrict__ out)
{
    const int tid = threadIdx.x;
    const int ln = tid & 63;
    const int w  = tid >> 6;
    const int lg = ln >> 4, lm = ln & 15;
    const int wr = w >> 1, wc = w & 1;
    const int bi = blockIdx.x;
    const int bn = bi & 7;
    const int bm = bi >> 3;
    const int r0 = bm * 64;
    const int n0 = bn * 128;

    __shared__ __align__(16) char lds[24576];

    f32x4 acc[2][4];
#pragma unroll
    for (int m = 0; m < 2; ++m)
#pragma unroll
        for (int n = 0; n < 4; ++n)
            acc[m][n] = {0.f, 0.f, 0.f, 0.f};

    const int srow = tid >> 3;
    const int sj   = tid & 7;
    const int swo  = srow * 128 + ((sj ^ (srow & 7)) << 4);

    const __hip_bfloat16* Ab = A  + (size_t)r0 * DMODEL;
    const __hip_bfloat16* Bb = Bt + (size_t)n0 * DMODEL;

    uint4 ar0 = *reinterpret_cast<const uint4*>(Ab + (size_t)srow        * DMODEL + sj * 8);
    uint4 ar1 = *reinterpret_cast<const uint4*>(Ab + (size_t)(srow + 32) * DMODEL + sj * 8);
    uint4 br0 = *reinterpret_cast<const uint4*>(Bb + (size_t)srow        * DMODEL + sj * 8);
    uint4 br1 = *reinterpret_cast<const uint4*>(Bb + (size_t)(srow + 32) * DMODEL + sj * 8);
    uint4 br2 = *reinterpret_cast<const uint4*>(Bb + (size_t)(srow + 64) * DMODEL + sj * 8);
    uint4 br3 = *reinterpret_cast<const uint4*>(Bb + (size_t)(srow + 96) * DMODEL + sj * 8);

    for (int k0 = 0; k0 < DMODEL; k0 += 64) {
        if (k0) __syncthreads();
        *reinterpret_cast<uint4*>(&lds[swo])          = ar0;
        *reinterpret_cast<uint4*>(&lds[swo + 4096])   = ar1;
        *reinterpret_cast<uint4*>(&lds[8192 + swo])           = br0;
        *reinterpret_cast<uint4*>(&lds[8192 + swo + 4096])    = br1;
        *reinterpret_cast<uint4*>(&lds[8192 + swo + 8192])    = br2;
        *reinterpret_cast<uint4*>(&lds[8192 + swo + 12288])   = br3;
        __syncthreads();
        if (k0 + 64 < DMODEL) {
            const __hip_bfloat16* An = Ab + k0 + 64;
            const __hip_bfloat16* Bn = Bb + k0 + 64;
            ar0 = *reinterpret_cast<const uint4*>(An + (size_t)srow        * DMODEL + sj * 8);
            ar1 = *reinterpret_cast<const uint4*>(An + (size_t)(srow + 32) * DMODEL + sj * 8);
            br0 = *reinterpret_cast<const uint4*>(Bn + (size_t)srow        * DMODEL + sj * 8);
            br1 = *reinterpret_cast<const uint4*>(Bn + (size_t)(srow + 32) * DMODEL + sj * 8);
            br2 = *reinterpret_cast<const uint4*>(Bn + (size_t)(srow + 64) * DMODEL + sj * 8);
            br3 = *reinterpret_cast<const uint4*>(Bn + (size_t)(srow + 96) * DMODEL + sj * 8);
        }

#pragma unroll
        for (int kh = 0; kh < 2; ++kh) {
            bf16x8 af[2], bf[4];
#pragma unroll
            for (int m = 0; m < 2; ++m) {
                int row = wr * 32 + m * 16 + lm;
                af[m] = *reinterpret_cast<const bf16x8*>(
                    &lds[row * 128 + (((kh * 4 + lg) ^ (row & 7)) << 4)]);
            }
#pragma unroll
            for (int n = 0; n < 4; ++n) {
                int row = wc * 64 + n * 16 + lm;
                bf[n] = *reinterpret_cast<const bf16x8*>(
                    &lds[8192 + row * 128 + (((kh * 4 + lg) ^ (row & 7)) << 4)]);
            }
#pragma unroll
            for (int m = 0; m < 2; ++m)
#pragma unroll
                for (int n = 0; n < 4; ++n)
                    acc[m][n] = __builtin_amdgcn_mfma_f32_16x16x32_bf16(
                        af[m], bf[n], acc[m][n], 0, 0, 0);
        }
    }

#pragma unroll
    for (int n = 0; n < 4; ++n) {
        int col = n0 + wc * 64 + n * 16 + lm;
        float bv = bo[col];
#pragma unroll
        for (int m = 0; m < 2; ++m) {
#pragma unroll
            for (int r = 0; r < 4; ++r) {
                int row = r0 + wr * 32 + m * 16 + lg * 4 + r;
                out[(size_t)row * DMODEL + col] = acc[m][n][r] + bv;
            }
        }
    }
}

// ---------------------------------------------------------------------------
extern "C" void kernel_launch(void* const* d_in, const int* in_sizes, int n_in,
                              void* d_out, int out_size, void* d_ws, size_t ws_size,
                              hipStream_t stream)
{
    const float* x  = (const float*)d_in[0];
    const float* wq = (const float*)d_in[1];
    const float* bq = (const float*)d_in[2];
    const float* wk = (const float*)d_in[3];
    const float* bk = (const float*)d_in[4];
    const float* wv = (const float*)d_in[5];
    const float* bv = (const float*)d_in[6];
    const float* wo = (const float*)d_in[7];
    const float* bo = (const float*)d_in[8];
    float* out = (float*)d_out;

    char* ws = (char*)d_ws;
    __hip_bfloat16* qws  = (__hip_bfloat16*)(ws);                        // 8 MB
    __hip_bfloat16* kws  = (__hip_bfloat16*)(ws + ((size_t)8  << 20));   // 8 MB
    __hip_bfloat16* vtws = (__hip_bfloat16*)(ws + ((size_t)16 << 20));   // 8 MB
    __hip_bfloat16* cws  = (__hip_bfloat16*)(ws + ((size_t)24 << 20));   // 8 MB
    __hip_bfloat16* wot  = (__hip_bfloat16*)(ws + ((size_t)32 << 20));   // 2 MB

    qkv_mfma<<<1024, 256, 0, stream>>>(
        x, wq, bq, wk, bk, wv, bv, qws, kws, vtws);
    wo_transpose<<<dim3(16, 16), 256, 0, stream>>>(wo, wot);
    attn_kernel<<<NB * NH * (S_LEN / 64), 256, 0, stream>>>(qws, kws, vtws, cws);
    out_gemm<<<(NB * S_LEN / 64) * (DMODEL / 128), 256, 0, stream>>>(
        cws, wot, bo, out);
}

// Round 14
// 97.850 us; speedup vs baseline: 1.0216x; 1.0054x over previous
//
#include <hip/hip_runtime.h>
#include <hip/hip_bf16.h>

typedef __attribute__((ext_vector_type(8))) short bf16x8;
typedef __attribute__((ext_vector_type(4))) short bf16x4;
typedef __attribute__((ext_vector_type(4))) float f32x4;

#if defined(__has_builtin)
#if __has_builtin(__builtin_amdgcn_exp2f)
#define EXP2F(x) __builtin_amdgcn_exp2f(x)
#else
#define EXP2F(x) exp2f(x)
#endif
#else
#define EXP2F(x) exp2f(x)
#endif

#define S_LEN 2048
#define NH 32
#define HD 32
#define DMODEL 1024
#define NB 2

// pack two fp32 -> two bf16 (RNE) in one instruction
static __device__ __forceinline__ unsigned int cvt_pk_bf16(float lo, float hi) {
    unsigned int r;
    asm("v_cvt_pk_bf16_f32 %0, %1, %2" : "=v"(r) : "v"(lo), "v"(hi));
    return r;
}

// K=16 bf16 MFMA, accumulate-only use (D read once, in the epilogue).
// R13-verified (passed, absmax 0.0049).
static __device__ __forceinline__ void mfma16_acc(f32x4& d, bf16x4 a, bf16x4 b) {
    asm("s_nop 2\n\tv_mfma_f32_16x16x16_bf16 %0, %1, %2, %0"
        : "+v"(d) : "v"(a), "v"(b));
}

// ---------------------------------------------------------------------------
// Kernel 1: MFMA QKV projection (R11-verified, unchanged)
// ---------------------------------------------------------------------------
__global__ __launch_bounds__(256) void qkv_mfma(
    const float* __restrict__ x,
    const float* __restrict__ wq, const float* __restrict__ bq,
    const float* __restrict__ wk, const float* __restrict__ bk,
    const float* __restrict__ wv, const float* __restrict__ bv,
    __hip_bfloat16* __restrict__ qws,
    __hip_bfloat16* __restrict__ kws,
    __hip_bfloat16* __restrict__ vtws)
{
    const int tid = threadIdx.x;
    const int w  = tid >> 6;
    const int ln = tid & 63;
    const int lg = ln >> 4, lm = ln & 15;

    const int bi = blockIdx.x;          // 0..1023
    const int tb = bi >> 2;             // token-16 block 0..255
    const int hq = bi & 3;              // head quarter
    const int t0 = tb * 16;             // flat token base (b*S + s)
    const int b  = t0 >> 11;
    const int s0 = t0 & 2047;

    const float SC = 0.1767766953f * 1.44269504089f;

    bf16x8 wqB[2], wkB[2], wvA[2];
    f32x4 bqC[2], bkC[2], bvC[2];
#pragma unroll
    for (int et = 0; et < 2; ++et) {
        const int e = et * 16 + lm;
        union { unsigned int u4[4]; bf16x8 v; } tq, tk, tv;
#pragma unroll
        for (int jj = 0; jj < 4; ++jj) {
            int k0 = lg * 8 + jj * 2;
            tq.u4[jj] = cvt_pk_bf16(wq[k0 * 32 + e] * SC, wq[(k0 + 1) * 32 + e] * SC);
            tk.u4[jj] = cvt_pk_bf16(wk[k0 * 32 + e],      wk[(k0 + 1) * 32 + e]);
            tv.u4[jj] = cvt_pk_bf16(wv[k0 * 32 + e],      wv[(k0 + 1) * 32 + e]);
        }
        wqB[et] = tq.v; wkB[et] = tk.v; wvA[et] = tv.v;

        float bqe = bq[e] * SC;
        float bke = bk[e];
        bqC[et] = (f32x4){bqe, bqe, bqe, bqe};
        bkC[et] = (f32x4){bke, bke, bke, bke};
#pragma unroll
        for (int r = 0; r < 4; ++r)
            bvC[et][r] = bv[et * 16 + lg * 4 + r];
    }

#pragma unroll
    for (int u = 0; u < 2; ++u) {
        const int h = hq * 8 + w * 2 + u;

        const float* xp = x + (size_t)(t0 + lm) * DMODEL + h * 32 + lg * 8;
        float4 xlo = *reinterpret_cast<const float4*>(xp);
        float4 xhi = *reinterpret_cast<const float4*>(xp + 4);
        union { unsigned int u4[4]; bf16x8 v; } xa;
        xa.u4[0] = cvt_pk_bf16(xlo.x, xlo.y);
        xa.u4[1] = cvt_pk_bf16(xlo.z, xlo.w);
        xa.u4[2] = cvt_pk_bf16(xhi.x, xhi.y);
        xa.u4[3] = cvt_pk_bf16(xhi.z, xhi.w);

        const int bh = b * NH + h;
        __hip_bfloat16* qrow = qws + ((size_t)bh * S_LEN + s0) * HD;
        __hip_bfloat16* krow = kws + ((size_t)bh * S_LEN + s0) * HD;
        __hip_bfloat16* vrow = vtws + (size_t)bh * HD * S_LEN + s0;

#pragma unroll
        for (int et = 0; et < 2; ++et) {
            f32x4 qd = __builtin_amdgcn_mfma_f32_16x16x32_bf16(xa.v, wqB[et], bqC[et], 0, 0, 0);
            f32x4 kd = __builtin_amdgcn_mfma_f32_16x16x32_bf16(xa.v, wkB[et], bkC[et], 0, 0, 0);
            f32x4 vd = __builtin_amdgcn_mfma_f32_16x16x32_bf16(wvA[et], xa.v, bvC[et], 0, 0, 0);
#pragma unroll
            for (int r = 0; r < 4; ++r) {
                int srow = 4 * lg + r;
                qrow[(size_t)srow * HD + et * 16 + lm] = __float2bfloat16(qd[r]);
                krow[(size_t)srow * HD + et * 16 + lm] = __float2bfloat16(kd[r]);
                vrow[(size_t)(et * 16 + 4 * lg + r) * S_LEN + lm] = __float2bfloat16(vd[r]);
            }
        }
    }
}

// ---------------------------------------------------------------------------
// Kernel 2: wo [K][N] fp32 -> wot [N][K] bf16 (unchanged, verified)
// ---------------------------------------------------------------------------
__global__ __launch_bounds__(256) void wo_transpose(
    const float* __restrict__ wo, __hip_bfloat16* __restrict__ wot)
{
    __shared__ float t[64][65];
    const int bx = blockIdx.x;
    const int by = blockIdx.y;
    const int tid = threadIdx.x;
    const int col = tid & 63, row4 = tid >> 6;
#pragma unroll
    for (int i = 0; i < 16; ++i) {
        int r = i * 4 + row4;
        t[r][col] = wo[(size_t)(bx * 64 + r) * DMODEL + by * 64 + col];
    }
    __syncthreads();
#pragma unroll
    for (int i = 0; i < 16; ++i) {
        int r = i * 4 + row4;
        wot[(size_t)(by * 64 + r) * DMODEL + bx * 64 + col] =
            __float2bfloat16(t[col][r]);
    }
}

// ---------------------------------------------------------------------------
// Kernel 3: flash attention — R13 body, TWO KV sub-tiles per barrier pair.
// LDS 16KB: [K0 4KB | V0 4KB | K1 4KB | V1 4KB]; each sub-tile byte-identical
// to the R13-passing layout. 16 super-iterations, 2 barriers each (was 32x2).
// s_setprio(1) around MFMA clusters (T5, attn-proven).
// ---------------------------------------------------------------------------
__global__ __launch_bounds__(256) void attn_kernel(
    const __hip_bfloat16* __restrict__ qws,
    const __hip_bfloat16* __restrict__ kws,
    const __hip_bfloat16* __restrict__ vtws,
    __hip_bfloat16* __restrict__ cws)
{
    const int tid = threadIdx.x;
    const int w  = tid >> 6;
    const int ln = tid & 63;
    const int lg = ln >> 4;   // 16-lane group 0..3
    const int lm = ln & 15;

    // XCD-aware decode (R5-verified): heads 8x..8x+7 pinned to XCD x
    const int bi  = blockIdx.x;
    const int xcd = bi & 7;
    const int idx = bi >> 3;                   // 0..255
    const int qt  = idx & 31;
    const int bh  = (xcd << 3) | (idx >> 5);   // b*32+h
    const int b   = bh >> 5;
    const int h   = bh & 31;

    const __hip_bfloat16* qp = qws + (size_t)bh * S_LEN * HD;
    const char* kpb = (const char*)(kws  + (size_t)bh * S_LEN * HD);
    const char* vpb = (const char*)(vtws + (size_t)bh * HD * S_LEN);

    const int qr0 = qt * 64 + w * 16;

    // Q as B-fragment: col = q = lm, k = d = lg*8+j
    bf16x8 qb = *reinterpret_cast<const bf16x8*>(qp + (size_t)(qr0 + lm) * HD + lg * 8);

    // LDS: [K0 | V0 | K1 | V1], each 4KB; V tiles 16B-slot swizzled
    __shared__ __align__(16) char kv[16384];

    f32x4 l4 = {0.f, 0.f, 0.f, 0.f};
    f32x4 o0 = {0.f, 0.f, 0.f, 0.f};   // O^T[d=4lg+r][q=lm]
    f32x4 o1 = {0.f, 0.f, 0.f, 0.f};   // O^T[16+4lg+r][q=lm]
    const f32x4 zoff = {-8.f, -8.f, -8.f, -8.f};

    // staging addresses (R13-verified per sub-tile)
    const int vrow  = tid >> 3;                       // V^T row (d), 0..31
    const int vslot = tid & 7;                        // 16B slot within row
    const size_t vsrc = (size_t)vrow * (S_LEN * 2) +
                        (size_t)(vslot ^ (vrow & 7)) * 16;   // swizzled source

    // V-read LDS byte offsets (loop-invariant, relative to sub-tile base)
    int voff[4];
#pragma unroll
    for (int c = 0; c < 4; ++c)
        voff[c] = 4096 + lm * 128 + (((2 * c + (lg >> 1)) ^ (lm & 7)) << 4) + (lg & 1) * 8;

    const int NT2 = S_LEN / 128;   // 16 super-iterations

    // prologue: load super-tile 0 (two sub-tiles) into registers
    uint4 kregA = *reinterpret_cast<const uint4*>(kpb + tid * 16);
    uint4 vregA = *reinterpret_cast<const uint4*>(vpb + vsrc);
    uint4 kregB = *reinterpret_cast<const uint4*>(kpb + 4096 + tid * 16);
    uint4 vregB = *reinterpret_cast<const uint4*>(vpb + vsrc + 128);

    for (int kt = 0; kt < NT2; ++kt) {
        if (kt) __syncthreads();                      // readers done with buffer
        *reinterpret_cast<uint4*>(&kv[tid * 16])         = kregA;
        *reinterpret_cast<uint4*>(&kv[4096 + tid * 16])  = vregA;
        *reinterpret_cast<uint4*>(&kv[8192 + tid * 16])  = kregB;
        *reinterpret_cast<uint4*>(&kv[12288 + tid * 16]) = vregB;
        __syncthreads();                              // staged data visible
        if (kt + 1 < NT2) {                           // issue next loads now
            kregA = *reinterpret_cast<const uint4*>(
                kpb + (size_t)(kt + 1) * 8192 + tid * 16);
            vregA = *reinterpret_cast<const uint4*>(
                vpb + vsrc + (size_t)(kt + 1) * 256);
            kregB = *reinterpret_cast<const uint4*>(
                kpb + (size_t)(kt + 1) * 8192 + 4096 + tid * 16);
            vregB = *reinterpret_cast<const uint4*>(
                vpb + vsrc + (size_t)(kt + 1) * 256 + 128);
        }

#pragma unroll
        for (int sub = 0; sub < 2; ++sub) {
            const char* base = &kv[sub * 8192];

            // S^T chunks: s[c][r] = score(q=lm, kv=...) - 8
            f32x4 s[4];
            __builtin_amdgcn_s_setprio(1);
#pragma unroll
            for (int c = 0; c < 4; ++c) {
                bf16x8 kf = *reinterpret_cast<const bf16x8*>(
                    base + c * 1024 + lm * 64 + lg * 16);
                s[c] = __builtin_amdgcn_mfma_f32_16x16x32_bf16(kf, qb, zoff, 0, 0, 0);
            }
            __builtin_amdgcn_s_setprio(0);

            // p = exp2(s-8); accumulate denominator; pack to K=16 B-frags
            bf16x4 pb[4];
#pragma unroll
            for (int c = 0; c < 4; ++c) {
                float p0 = EXP2F(s[c][0]);
                float p1 = EXP2F(s[c][1]);
                float p2 = EXP2F(s[c][2]);
                float p3 = EXP2F(s[c][3]);
                l4[0] += p0; l4[1] += p1; l4[2] += p2; l4[3] += p3;
                union { unsigned int u[2]; bf16x4 v; } pk_;
                pk_.u[0] = cvt_pk_bf16(p0, p1);
                pk_.u[1] = cvt_pk_bf16(p2, p3);
                pb[c] = pk_.v;
            }

            // PV: O^T += V^T * P^T, K=16 per kv-chunk, P from registers
            __builtin_amdgcn_s_setprio(1);
#pragma unroll
            for (int c = 0; c < 4; ++c) {
                bf16x4 va = *reinterpret_cast<const bf16x4*>(base + voff[c]);
                bf16x4 vb = *reinterpret_cast<const bf16x4*>(base + voff[c] + 2048);
                mfma16_acc(o0, va, pb[c]);
                mfma16_acc(o1, vb, pb[c]);
            }
            __builtin_amdgcn_s_setprio(0);
        }
    }

    // MFMA->VALU read-of-D hazard guard (one-time), then epilogue
    asm volatile("s_nop 7\n\ts_nop 7");

    float l = (l4[0] + l4[1]) + (l4[2] + l4[3]);
    l += __shfl_xor(l, 16);
    l += __shfl_xor(l, 32);
    float inv = 1.0f / l;

    __hip_bfloat16* cb = cws + ((size_t)b * S_LEN + qr0 + lm) * DMODEL + h * HD;
    union { unsigned int u[2]; bf16x4 v; } w0, w1;
    w0.u[0] = cvt_pk_bf16(o0[0] * inv, o0[1] * inv);
    w0.u[1] = cvt_pk_bf16(o0[2] * inv, o0[3] * inv);
    w1.u[0] = cvt_pk_bf16(o1[0] * inv, o1[1] * inv);
    w1.u[1] = cvt_pk_bf16(o1[2] * inv, o1[3] * inv);
    *reinterpret_cast<bf16x4*>(cb + lg * 4)      = w0.v;
    *reinterpret_cast<bf16x4*>(cb + 16 + lg * 4) = w1.v;
}

// ---------------------------------------------------------------------------
// Kernel 4: out = concat @ wo + bo — LDS-tiled (unchanged from R8, verified)
// ---------------------------------------------------------------------------
__global__ __launch_bounds__(256) void out_gemm(
    const __hip_bfloat16* __restrict__ A,
    const __hip_bfloat16* __restrict__ Bt,
    const float* __restrict__ bo,
    float* __restrict__ out)
{
    const int tid = threadIdx.x;
    const int ln = tid & 63;
    const int w  = tid >> 6;
    const int lg = ln >> 4, lm = ln & 15;
    const int wr = w >> 1, wc = w & 1;
    const int bi = blockIdx.x;
    const int bn = bi & 7;
    const int bm = bi >> 3;
    const int r0 = bm * 64;
    const int n0 = bn * 128;

    __shared__ __align__(16) char lds[24576];

    f32x4 acc[2][4];
#pragma unroll
    for (int m = 0; m < 2; ++m)
#pragma unroll
        for (int n = 0; n < 4; ++n)
            acc[m][n] = {0.f, 0.f, 0.f, 0.f};

    const int srow = tid >> 3;
    const int sj   = tid & 7;
    const int swo  = srow * 128 + ((sj ^ (srow & 7)) << 4);

    const __hip_bfloat16* Ab = A  + (size_t)r0 * DMODEL;
    const __hip_bfloat16* Bb = Bt + (size_t)n0 * DMODEL;

    uint4 ar0 = *reinterpret_cast<const uint4*>(Ab + (size_t)srow        * DMODEL + sj * 8);
    uint4 ar1 = *reinterpret_cast<const uint4*>(Ab + (size_t)(srow + 32) * DMODEL + sj * 8);
    uint4 br0 = *reinterpret_cast<const uint4*>(Bb + (size_t)srow        * DMODEL + sj * 8);
    uint4 br1 = *reinterpret_cast<const uint4*>(Bb + (size_t)(srow + 32) * DMODEL + sj * 8);
    uint4 br2 = *reinterpret_cast<const uint4*>(Bb + (size_t)(srow + 64) * DMODEL + sj * 8);
    uint4 br3 = *reinterpret_cast<const uint4*>(Bb + (size_t)(srow + 96) * DMODEL + sj * 8);

    for (int k0 = 0; k0 < DMODEL; k0 += 64) {
        if (k0) __syncthreads();
        *reinterpret_cast<uint4*>(&lds[swo])          = ar0;
        *reinterpret_cast<uint4*>(&lds[swo + 4096])   = ar1;
        *reinterpret_cast<uint4*>(&lds[8192 + swo])           = br0;
        *reinterpret_cast<uint4*>(&lds[8192 + swo + 4096])    = br1;
        *reinterpret_cast<uint4*>(&lds[8192 + swo + 8192])    = br2;
        *reinterpret_cast<uint4*>(&lds[8192 + swo + 12288])   = br3;
        __syncthreads();
        if (k0 + 64 < DMODEL) {
            const __hip_bfloat16* An = Ab + k0 + 64;
            const __hip_bfloat16* Bn = Bb + k0 + 64;
            ar0 = *reinterpret_cast<const uint4*>(An + (size_t)srow        * DMODEL + sj * 8);
            ar1 = *reinterpret_cast<const uint4*>(An + (size_t)(srow + 32) * DMODEL + sj * 8);
            br0 = *reinterpret_cast<const uint4*>(Bn + (size_t)srow        * DMODEL + sj * 8);
            br1 = *reinterpret_cast<const uint4*>(Bn + (size_t)(srow + 32) * DMODEL + sj * 8);
            br2 = *reinterpret_cast<const uint4*>(Bn + (size_t)(srow + 64) * DMODEL + sj * 8);
            br3 = *reinterpret_cast<const uint4*>(Bn + (size_t)(srow + 96) * DMODEL + sj * 8);
        }

#pragma unroll
        for (int kh = 0; kh < 2; ++kh) {
            bf16x8 af[2], bf[4];
#pragma unroll
            for (int m = 0; m < 2; ++m) {
                int row = wr * 32 + m * 16 + lm;
                af[m] = *reinterpret_cast<const bf16x8*>(
                    &lds[row * 128 + (((kh * 4 + lg) ^ (row & 7)) << 4)]);
            }
#pragma unroll
            for (int n = 0; n < 4; ++n) {
                int row = wc * 64 + n * 16 + lm;
                bf[n] = *reinterpret_cast<const bf16x8*>(
                    &lds[8192 + row * 128 + (((kh * 4 + lg) ^ (row & 7)) << 4)]);
            }
#pragma unroll
            for (int m = 0; m < 2; ++m)
#pragma unroll
                for (int n = 0; n < 4; ++n)
                    acc[m][n] = __builtin_amdgcn_mfma_f32_16x16x32_bf16(
                        af[m], bf[n], acc[m][n], 0, 0, 0);
        }
    }

#pragma unroll
    for (int n = 0; n < 4; ++n) {
        int col = n0 + wc * 64 + n * 16 + lm;
        float bv = bo[col];
#pragma unroll
        for (int m = 0; m < 2; ++m) {
#pragma unroll
            for (int r = 0; r < 4; ++r) {
                int row = r0 + wr * 32 + m * 16 + lg * 4 + r;
                out[(size_t)row * DMODEL + col] = acc[m][n][r] + bv;
            }
        }
    }
}

// ---------------------------------------------------------------------------
extern "C" void kernel_launch(void* const* d_in, const int* in_sizes, int n_in,
                              void* d_out, int out_size, void* d_ws, size_t ws_size,
                              hipStream_t stream)
{
    const float* x  = (const float*)d_in[0];
    const float* wq = (const float*)d_in[1];
    const float* bq = (const float*)d_in[2];
    const float* wk = (const float*)d_in[3];
    const float* bk = (const float*)d_in[4];
    const float* wv = (const float*)d_in[5];
    const float* bv = (const float*)d_in[6];
    const float* wo = (const float*)d_in[7];
    const float* bo = (const float*)d_in[8];
    float* out = (float*)d_out;

    char* ws = (char*)d_ws;
    __hip_bfloat16* qws  = (__hip_bfloat16*)(ws);                        // 8 MB
    __hip_bfloat16* kws  = (__hip_bfloat16*)(ws + ((size_t)8  << 20));   // 8 MB
    __hip_bfloat16* vtws = (__hip_bfloat16*)(ws + ((size_t)16 << 20));   // 8 MB
    __hip_bfloat16* cws  = (__hip_bfloat16*)(ws + ((size_t)24 << 20));   // 8 MB
    __hip_bfloat16* wot  = (__hip_bfloat16*)(ws + ((size_t)32 << 20));   // 2 MB

    qkv_mfma<<<1024, 256, 0, stream>>>(
        x, wq, bq, wk, bk, wv, bv, qws, kws, vtws);
    wo_transpose<<<dim3(16, 16), 256, 0, stream>>>(wo, wot);
    attn_kernel<<<NB * NH * (S_LEN / 64), 256, 0, stream>>>(qws, kws, vtws, cws);
    out_gemm<<<(NB * S_LEN / 64) * (DMODEL / 128), 256, 0, stream>>>(
        cws, wot, bo, out);
}

// Round 15
// 96.376 us; speedup vs baseline: 1.0372x; 1.0153x over previous
//
#include <hip/hip_runtime.h>
#include <hip/hip_bf16.h>

typedef __attribute__((ext_vector_type(8))) short bf16x8;
typedef __attribute__((ext_vector_type(4))) short bf16x4;
typedef __attribute__((ext_vector_type(4))) float f32x4;

#if defined(__has_builtin)
#if __has_builtin(__builtin_amdgcn_exp2f)
#define EXP2F(x) __builtin_amdgcn_exp2f(x)
#else
#define EXP2F(x) exp2f(x)
#endif
#else
#define EXP2F(x) exp2f(x)
#endif

#define S_LEN 2048
#define NH 32
#define HD 32
#define DMODEL 1024
#define NB 2

// pack two fp32 -> two bf16 (RNE) in one instruction
static __device__ __forceinline__ unsigned int cvt_pk_bf16(float lo, float hi) {
    unsigned int r;
    asm("v_cvt_pk_bf16_f32 %0, %1, %2" : "=v"(r) : "v"(lo), "v"(hi));
    return r;
}

// K=16 bf16 MFMA, accumulate-only use (D read once, in the epilogue).
// R13/R14-verified (passed, absmax 0.0049).
static __device__ __forceinline__ void mfma16_acc(f32x4& d, bf16x4 a, bf16x4 b) {
    asm("s_nop 2\n\tv_mfma_f32_16x16x16_bf16 %0, %1, %2, %0"
        : "+v"(d) : "v"(a), "v"(b));
}

// ---------------------------------------------------------------------------
// Kernel 1: MFMA QKV projection (R11-verified, unchanged)
// ---------------------------------------------------------------------------
__global__ __launch_bounds__(256) void qkv_mfma(
    const float* __restrict__ x,
    const float* __restrict__ wq, const float* __restrict__ bq,
    const float* __restrict__ wk, const float* __restrict__ bk,
    const float* __restrict__ wv, const float* __restrict__ bv,
    __hip_bfloat16* __restrict__ qws,
    __hip_bfloat16* __restrict__ kws,
    __hip_bfloat16* __restrict__ vtws)
{
    const int tid = threadIdx.x;
    const int w  = tid >> 6;
    const int ln = tid & 63;
    const int lg = ln >> 4, lm = ln & 15;

    const int bi = blockIdx.x;          // 0..1023
    const int tb = bi >> 2;             // token-16 block 0..255
    const int hq = bi & 3;              // head quarter
    const int t0 = tb * 16;             // flat token base (b*S + s)
    const int b  = t0 >> 11;
    const int s0 = t0 & 2047;

    const float SC = 0.1767766953f * 1.44269504089f;

    bf16x8 wqB[2], wkB[2], wvA[2];
    f32x4 bqC[2], bkC[2], bvC[2];
#pragma unroll
    for (int et = 0; et < 2; ++et) {
        const int e = et * 16 + lm;
        union { unsigned int u4[4]; bf16x8 v; } tq, tk, tv;
#pragma unroll
        for (int jj = 0; jj < 4; ++jj) {
            int k0 = lg * 8 + jj * 2;
            tq.u4[jj] = cvt_pk_bf16(wq[k0 * 32 + e] * SC, wq[(k0 + 1) * 32 + e] * SC);
            tk.u4[jj] = cvt_pk_bf16(wk[k0 * 32 + e],      wk[(k0 + 1) * 32 + e]);
            tv.u4[jj] = cvt_pk_bf16(wv[k0 * 32 + e],      wv[(k0 + 1) * 32 + e]);
        }
        wqB[et] = tq.v; wkB[et] = tk.v; wvA[et] = tv.v;

        float bqe = bq[e] * SC;
        float bke = bk[e];
        bqC[et] = (f32x4){bqe, bqe, bqe, bqe};
        bkC[et] = (f32x4){bke, bke, bke, bke};
#pragma unroll
        for (int r = 0; r < 4; ++r)
            bvC[et][r] = bv[et * 16 + lg * 4 + r];
    }

#pragma unroll
    for (int u = 0; u < 2; ++u) {
        const int h = hq * 8 + w * 2 + u;

        const float* xp = x + (size_t)(t0 + lm) * DMODEL + h * 32 + lg * 8;
        float4 xlo = *reinterpret_cast<const float4*>(xp);
        float4 xhi = *reinterpret_cast<const float4*>(xp + 4);
        union { unsigned int u4[4]; bf16x8 v; } xa;
        xa.u4[0] = cvt_pk_bf16(xlo.x, xlo.y);
        xa.u4[1] = cvt_pk_bf16(xlo.z, xlo.w);
        xa.u4[2] = cvt_pk_bf16(xhi.x, xhi.y);
        xa.u4[3] = cvt_pk_bf16(xhi.z, xhi.w);

        const int bh = b * NH + h;
        __hip_bfloat16* qrow = qws + ((size_t)bh * S_LEN + s0) * HD;
        __hip_bfloat16* krow = kws + ((size_t)bh * S_LEN + s0) * HD;
        __hip_bfloat16* vrow = vtws + (size_t)bh * HD * S_LEN + s0;

#pragma unroll
        for (int et = 0; et < 2; ++et) {
            f32x4 qd = __builtin_amdgcn_mfma_f32_16x16x32_bf16(xa.v, wqB[et], bqC[et], 0, 0, 0);
            f32x4 kd = __builtin_amdgcn_mfma_f32_16x16x32_bf16(xa.v, wkB[et], bkC[et], 0, 0, 0);
            f32x4 vd = __builtin_amdgcn_mfma_f32_16x16x32_bf16(wvA[et], xa.v, bvC[et], 0, 0, 0);
#pragma unroll
            for (int r = 0; r < 4; ++r) {
                int srow = 4 * lg + r;
                qrow[(size_t)srow * HD + et * 16 + lm] = __float2bfloat16(qd[r]);
                krow[(size_t)srow * HD + et * 16 + lm] = __float2bfloat16(kd[r]);
                vrow[(size_t)(et * 16 + 4 * lg + r) * S_LEN + lm] = __float2bfloat16(vd[r]);
            }
        }
    }
}

// ---------------------------------------------------------------------------
// Kernel 2: wo [K][N] fp32 -> wot [N][K] bf16 (unchanged, verified)
// ---------------------------------------------------------------------------
__global__ __launch_bounds__(256) void wo_transpose(
    const float* __restrict__ wo, __hip_bfloat16* __restrict__ wot)
{
    __shared__ float t[64][65];
    const int bx = blockIdx.x;
    const int by = blockIdx.y;
    const int tid = threadIdx.x;
    const int col = tid & 63, row4 = tid >> 6;
#pragma unroll
    for (int i = 0; i < 16; ++i) {
        int r = i * 4 + row4;
        t[r][col] = wo[(size_t)(bx * 64 + r) * DMODEL + by * 64 + col];
    }
    __syncthreads();
#pragma unroll
    for (int i = 0; i < 16; ++i) {
        int r = i * 4 + row4;
        wot[(size_t)(by * 64 + r) * DMODEL + bx * 64 + col] =
            __float2bfloat16(t[col][r]);
    }
}

// ---------------------------------------------------------------------------
// Kernel 3: flash attention — R14 structure + K-TILE BANK SWIZZLE.
// K rows are 64B (16 dwords): linear layout collapses each 16-lane read
// phase onto 2 bank-quads (8-way conflict, the measured 12.6M cycles).
// Fix: 16B-slot index ^= (row>>1)&3, applied on the staging SOURCE address
// (LDS dest stays linear) and on the read offset — same involution
// discipline as the proven V swizzle. Post-swizzle: 2-way (free).
// Everything else byte-identical to the R14 passing kernel.
// ---------------------------------------------------------------------------
__global__ __launch_bounds__(256) void attn_kernel(
    const __hip_bfloat16* __restrict__ qws,
    const __hip_bfloat16* __restrict__ kws,
    const __hip_bfloat16* __restrict__ vtws,
    __hip_bfloat16* __restrict__ cws)
{
    const int tid = threadIdx.x;
    const int w  = tid >> 6;
    const int ln = tid & 63;
    const int lg = ln >> 4;   // 16-lane group 0..3
    const int lm = ln & 15;

    // XCD-aware decode (R5-verified): heads 8x..8x+7 pinned to XCD x
    const int bi  = blockIdx.x;
    const int xcd = bi & 7;
    const int idx = bi >> 3;                   // 0..255
    const int qt  = idx & 31;
    const int bh  = (xcd << 3) | (idx >> 5);   // b*32+h
    const int b   = bh >> 5;
    const int h   = bh & 31;

    const __hip_bfloat16* qp = qws + (size_t)bh * S_LEN * HD;
    const char* kpb = (const char*)(kws  + (size_t)bh * S_LEN * HD);
    const char* vpb = (const char*)(vtws + (size_t)bh * HD * S_LEN);

    const int qr0 = qt * 64 + w * 16;

    // Q as B-fragment: col = q = lm, k = d = lg*8+j
    bf16x8 qb = *reinterpret_cast<const bf16x8*>(qp + (size_t)(qr0 + lm) * HD + lg * 8);

    // LDS: [K0 | V0 | K1 | V1], each 4KB; K and V tiles 16B-slot swizzled
    __shared__ __align__(16) char kv[16384];

    f32x4 l4 = {0.f, 0.f, 0.f, 0.f};
    f32x4 o0 = {0.f, 0.f, 0.f, 0.f};   // O^T[d=4lg+r][q=lm]
    f32x4 o1 = {0.f, 0.f, 0.f, 0.f};   // O^T[16+4lg+r][q=lm]
    const f32x4 zoff = {-8.f, -8.f, -8.f, -8.f};

    // ---- staging source addresses (per-thread constants) ----
    // V (R13/R14-verified): row=tid>>3, slot=tid&7, source slot ^= row&7
    const int vrow  = tid >> 3;
    const int vslot = tid & 7;
    const size_t vsrc = (size_t)vrow * (S_LEN * 2) +
                        (size_t)(vslot ^ (vrow & 7)) * 16;
    // K (NEW): row=tid>>2, slot=tid&3, source slot ^= (row>>1)&3
    const int krow  = tid >> 2;
    const int kslot = tid & 3;
    const size_t ksrc = (size_t)krow * 64 +
                        (size_t)(kslot ^ ((krow >> 1) & 3)) * 16;

    // ---- read offsets (loop-invariant) ----
    // K: row-local swizzle (chunk base c*1024 contributes 0 mod 4 to row>>1)
    const int krd = lm * 64 + ((lg ^ ((lm >> 1) & 3)) << 4);
    // V: slot' = (2c + (lg>>1)) ^ (lm&7), 8B element (lg&1)
    int voff[4];
#pragma unroll
    for (int c = 0; c < 4; ++c)
        voff[c] = 4096 + lm * 128 + (((2 * c + (lg >> 1)) ^ (lm & 7)) << 4) + (lg & 1) * 8;

    const int NT2 = S_LEN / 128;   // 16 super-iterations

    // prologue: load super-tile 0 (two sub-tiles) into registers
    uint4 kregA = *reinterpret_cast<const uint4*>(kpb + ksrc);
    uint4 vregA = *reinterpret_cast<const uint4*>(vpb + vsrc);
    uint4 kregB = *reinterpret_cast<const uint4*>(kpb + 4096 + ksrc);
    uint4 vregB = *reinterpret_cast<const uint4*>(vpb + vsrc + 128);

    for (int kt = 0; kt < NT2; ++kt) {
        if (kt) __syncthreads();                      // readers done with buffer
        *reinterpret_cast<uint4*>(&kv[tid * 16])         = kregA;
        *reinterpret_cast<uint4*>(&kv[4096 + tid * 16])  = vregA;
        *reinterpret_cast<uint4*>(&kv[8192 + tid * 16])  = kregB;
        *reinterpret_cast<uint4*>(&kv[12288 + tid * 16]) = vregB;
        __syncthreads();                              // staged data visible
        if (kt + 1 < NT2) {                           // issue next loads now
            kregA = *reinterpret_cast<const uint4*>(
                kpb + (size_t)(kt + 1) * 8192 + ksrc);
            vregA = *reinterpret_cast<const uint4*>(
                vpb + vsrc + (size_t)(kt + 1) * 256);
            kregB = *reinterpret_cast<const uint4*>(
                kpb + (size_t)(kt + 1) * 8192 + 4096 + ksrc);
            vregB = *reinterpret_cast<const uint4*>(
                vpb + vsrc + (size_t)(kt + 1) * 256 + 128);
        }

#pragma unroll
        for (int sub = 0; sub < 2; ++sub) {
            const char* base = &kv[sub * 8192];

            // S^T chunks: s[c][r] = score(q=lm, kv=...) - 8
            f32x4 s[4];
            __builtin_amdgcn_s_setprio(1);
#pragma unroll
            for (int c = 0; c < 4; ++c) {
                bf16x8 kf = *reinterpret_cast<const bf16x8*>(
                    base + c * 1024 + krd);
                s[c] = __builtin_amdgcn_mfma_f32_16x16x32_bf16(kf, qb, zoff, 0, 0, 0);
            }
            __builtin_amdgcn_s_setprio(0);

            // p = exp2(s-8); accumulate denominator; pack to K=16 B-frags
            bf16x4 pb[4];
#pragma unroll
            for (int c = 0; c < 4; ++c) {
                float p0 = EXP2F(s[c][0]);
                float p1 = EXP2F(s[c][1]);
                float p2 = EXP2F(s[c][2]);
                float p3 = EXP2F(s[c][3]);
                l4[0] += p0; l4[1] += p1; l4[2] += p2; l4[3] += p3;
                union { unsigned int u[2]; bf16x4 v; } pk_;
                pk_.u[0] = cvt_pk_bf16(p0, p1);
                pk_.u[1] = cvt_pk_bf16(p2, p3);
                pb[c] = pk_.v;
            }

            // PV: O^T += V^T * P^T, K=16 per kv-chunk, P from registers
            __builtin_amdgcn_s_setprio(1);
#pragma unroll
            for (int c = 0; c < 4; ++c) {
                bf16x4 va = *reinterpret_cast<const bf16x4*>(base + voff[c]);
                bf16x4 vb = *reinterpret_cast<const bf16x4*>(base + voff[c] + 2048);
                mfma16_acc(o0, va, pb[c]);
                mfma16_acc(o1, vb, pb[c]);
            }
            __builtin_amdgcn_s_setprio(0);
        }
    }

    // MFMA->VALU read-of-D hazard guard (one-time), then epilogue
    asm volatile("s_nop 7\n\ts_nop 7");

    float l = (l4[0] + l4[1]) + (l4[2] + l4[3]);
    l += __shfl_xor(l, 16);
    l += __shfl_xor(l, 32);
    float inv = 1.0f / l;

    __hip_bfloat16* cb = cws + ((size_t)b * S_LEN + qr0 + lm) * DMODEL + h * HD;
    union { unsigned int u[2]; bf16x4 v; } w0, w1;
    w0.u[0] = cvt_pk_bf16(o0[0] * inv, o0[1] * inv);
    w0.u[1] = cvt_pk_bf16(o0[2] * inv, o0[3] * inv);
    w1.u[0] = cvt_pk_bf16(o1[0] * inv, o1[1] * inv);
    w1.u[1] = cvt_pk_bf16(o1[2] * inv, o1[3] * inv);
    *reinterpret_cast<bf16x4*>(cb + lg * 4)      = w0.v;
    *reinterpret_cast<bf16x4*>(cb + 16 + lg * 4) = w1.v;
}

// ---------------------------------------------------------------------------
// Kernel 4: out = concat @ wo + bo — LDS-tiled (unchanged from R8, verified)
// ---------------------------------------------------------------------------
__global__ __launch_bounds__(256) void out_gemm(
    const __hip_bfloat16* __restrict__ A,
    const __hip_bfloat16* __restrict__ Bt,
    const float* __restrict__ bo,
    float* __restrict__ out)
{
    const int tid = threadIdx.x;
    const int ln = tid & 63;
    const int w  = tid >> 6;
    const int lg = ln >> 4, lm = ln & 15;
    const int wr = w >> 1, wc = w & 1;
    const int bi = blockIdx.x;
    const int bn = bi & 7;
    const int bm = bi >> 3;
    const int r0 = bm * 64;
    const int n0 = bn * 128;

    __shared__ __align__(16) char lds[24576];

    f32x4 acc[2][4];
#pragma unroll
    for (int m = 0; m < 2; ++m)
#pragma unroll
        for (int n = 0; n < 4; ++n)
            acc[m][n] = {0.f, 0.f, 0.f, 0.f};

    const int srow = tid >> 3;
    const int sj   = tid & 7;
    const int swo  = srow * 128 + ((sj ^ (srow & 7)) << 4);

    const __hip_bfloat16* Ab = A  + (size_t)r0 * DMODEL;
    const __hip_bfloat16* Bb = Bt + (size_t)n0 * DMODEL;

    uint4 ar0 = *reinterpret_cast<const uint4*>(Ab + (size_t)srow        * DMODEL + sj * 8);
    uint4 ar1 = *reinterpret_cast<const uint4*>(Ab + (size_t)(srow + 32) * DMODEL + sj * 8);
    uint4 br0 = *reinterpret_cast<const uint4*>(Bb + (size_t)srow        * DMODEL + sj * 8);
    uint4 br1 = *reinterpret_cast<const uint4*>(Bb + (size_t)(srow + 32) * DMODEL + sj * 8);
    uint4 br2 = *reinterpret_cast<const uint4*>(Bb + (size_t)(srow + 64) * DMODEL + sj * 8);
    uint4 br3 = *reinterpret_cast<const uint4*>(Bb + (size_t)(srow + 96) * DMODEL + sj * 8);

    for (int k0 = 0; k0 < DMODEL; k0 += 64) {
        if (k0) __syncthreads();
        *reinterpret_cast<uint4*>(&lds[swo])          = ar0;
        *reinterpret_cast<uint4*>(&lds[swo + 4096])   = ar1;
        *reinterpret_cast<uint4*>(&lds[8192 + swo])           = br0;
        *reinterpret_cast<uint4*>(&lds[8192 + swo + 4096])    = br1;
        *reinterpret_cast<uint4*>(&lds[8192 + swo + 8192])    = br2;
        *reinterpret_cast<uint4*>(&lds[8192 + swo + 12288])   = br3;
        __syncthreads();
        if (k0 + 64 < DMODEL) {
            const __hip_bfloat16* An = Ab + k0 + 64;
            const __hip_bfloat16* Bn = Bb + k0 + 64;
            ar0 = *reinterpret_cast<const uint4*>(An + (size_t)srow        * DMODEL + sj * 8);
            ar1 = *reinterpret_cast<const uint4*>(An + (size_t)(srow + 32) * DMODEL + sj * 8);
            br0 = *reinterpret_cast<const uint4*>(Bn + (size_t)srow        * DMODEL + sj * 8);
            br1 = *reinterpret_cast<const uint4*>(Bn + (size_t)(srow + 32) * DMODEL + sj * 8);
            br2 = *reinterpret_cast<const uint4*>(Bn + (size_t)(srow + 64) * DMODEL + sj * 8);
            br3 = *reinterpret_cast<const uint4*>(Bn + (size_t)(srow + 96) * DMODEL + sj * 8);
        }

#pragma unroll
        for (int kh = 0; kh < 2; ++kh) {
            bf16x8 af[2], bf[4];
#pragma unroll
            for (int m = 0; m < 2; ++m) {
                int row = wr * 32 + m * 16 + lm;
                af[m] = *reinterpret_cast<const bf16x8*>(
                    &lds[row * 128 + (((kh * 4 + lg) ^ (row & 7)) << 4)]);
            }
#pragma unroll
            for (int n = 0; n < 4; ++n) {
                int row = wc * 64 + n * 16 + lm;
                bf[n] = *reinterpret_cast<const bf16x8*>(
                    &lds[8192 + row * 128 + (((kh * 4 + lg) ^ (row & 7)) << 4)]);
            }
#pragma unroll
            for (int m = 0; m < 2; ++m)
#pragma unroll
                for (int n = 0; n < 4; ++n)
                    acc[m][n] = __builtin_amdgcn_mfma_f32_16x16x32_bf16(
                        af[m], bf[n], acc[m][n], 0, 0, 0);
        }
    }

#pragma unroll
    for (int n = 0; n < 4; ++n) {
        int col = n0 + wc * 64 + n * 16 + lm;
        float bv = bo[col];
#pragma unroll
        for (int m = 0; m < 2; ++m) {
#pragma unroll
            for (int r = 0; r < 4; ++r) {
                int row = r0 + wr * 32 + m * 16 + lg * 4 + r;
                out[(size_t)row * DMODEL + col] = acc[m][n][r] + bv;
            }
        }
    }
}

// ---------------------------------------------------------------------------
extern "C" void kernel_launch(void* const* d_in, const int* in_sizes, int n_in,
                              void* d_out, int out_size, void* d_ws, size_t ws_size,
                              hipStream_t stream)
{
    const float* x  = (const float*)d_in[0];
    const float* wq = (const float*)d_in[1];
    const float* bq = (const float*)d_in[2];
    const float* wk = (const float*)d_in[3];
    const float* bk = (const float*)d_in[4];
    const float* wv = (const float*)d_in[5];
    const float* bv = (const float*)d_in[6];
    const float* wo = (const float*)d_in[7];
    const float* bo = (const float*)d_in[8];
    float* out = (float*)d_out;

    char* ws = (char*)d_ws;
    __hip_bfloat16* qws  = (__hip_bfloat16*)(ws);                        // 8 MB
    __hip_bfloat16* kws  = (__hip_bfloat16*)(ws + ((size_t)8  << 20));   // 8 MB
    __hip_bfloat16* vtws = (__hip_bfloat16*)(ws + ((size_t)16 << 20));   // 8 MB
    __hip_bfloat16* cws  = (__hip_bfloat16*)(ws + ((size_t)24 << 20));   // 8 MB
    __hip_bfloat16* wot  = (__hip_bfloat16*)(ws + ((size_t)32 << 20));   // 2 MB

    qkv_mfma<<<1024, 256, 0, stream>>>(
        x, wq, bq, wk, bk, wv, bv, qws, kws, vtws);
    wo_transpose<<<dim3(16, 16), 256, 0, stream>>>(wo, wot);
    attn_kernel<<<NB * NH * (S_LEN / 64), 256, 0, stream>>>(qws, kws, vtws, cws);
    out_gemm<<<(NB * S_LEN / 64) * (DMODEL / 128), 256, 0, stream>>>(
        cws, wot, bo, out);
}